// Round 9
// baseline (92.803 us; speedup 1.0000x reference)
//
#include <hip/hip_runtime.h>
#include <hip/hip_bf16.h>

// ---- problem constants ----
#define NB    30      // RBF basis count
#define TPTS  50      // rollout points
#define DOF   7
#define BATCH 4096
#define DIN   64
#define HID   256
#define OUTC  217     // N*DOF + DOF
#define STEPS 500     // T*L
#define DTF   0.002f  // TAU/(T*L)
#define DTD   0.002
#define AZD   15.0
#define C1D   56.25   // A_Z * B_Z = 15 * 3.75

// ---- workspace layout (bytes) ----
#define WS_QY     131072      // float [50][32]   = 6400 B
#define WS_QZ     139264      // float [50][32]
#define WS_CONST  147456      // float [8]
#define WS_WTPT   155648      // bf16 [256][64]   = 32768 B   (W_pt^T)
#define WS_WTLAST 188416      // bf16 [224][256]  = 114688 B  (W_last^T, zero-padded)

typedef __attribute__((ext_vector_type(8))) short short8;
typedef __attribute__((ext_vector_type(4))) float f32x4;

__device__ __forceinline__ short f2bf(float f) {
  unsigned u = __builtin_bit_cast(unsigned, f);
  unsigned r = (u + 0x7FFFu + ((u >> 16) & 1u)) >> 16;
  return (short)r;
}

__device__ __forceinline__ float tanh_fast(float v) {
  // 1 - 2/(e^{2v}+1); exact at +-inf, ~2^-21 rel error -> invisible after bf16
  float e = __expf(2.0f * v);
  return 1.0f - __fdividef(2.0f, e + 1.0f);
}

// ---------------------------------------------------------------------------
// Kernel 1: prep.
//  blocks 0..143 : weight cast+transpose (Wt_pt [256][64], Wt_last [224][256])
//  block  144    : Q/cst tables, fully parallel (no serial tail):
//                  x_t = powf(1-dt,t+1); inv_t = x_t/sum(psi)   (500 threads)
//                  Q_y/Q_z[k][n] composed in double              (1600 cells)
// ---------------------------------------------------------------------------
__global__ __launch_bounds__(512) void prep_kernel(
    const float* __restrict__ cbuf, const float* __restrict__ hbuf,
    const float* __restrict__ W_pt, const float* __restrict__ W_last,
    char* __restrict__ ws) {
  const int tid = threadIdx.x;

  if (blockIdx.x < 144) {
    short* Wt_pt   = (short*)(ws + WS_WTPT);     // [256][64]
    short* Wt_last = (short*)(ws + WS_WTLAST);   // [224][256]
    const int idx = blockIdx.x * 512 + tid;      // 144*512 = 73728 exactly
    if (idx < 256 * 64) {
      const int j = idx >> 6, k = idx & 63;
      Wt_pt[idx] = f2bf(W_pt[k * 256 + j]);
    } else {
      const int idx2 = idx - 256 * 64;
      const int col = idx2 >> 8, k = idx2 & 255;
      Wt_last[idx2] = (col < OUTC) ? f2bf(W_last[k * OUTC + col]) : (short)0;
    }
    return;
  }

  // ---- Q block ----
  __shared__ float xs[STEPS];
  __shared__ float inv[STEPS];
  float* Qy  = (float*)(ws + WS_QY);
  float* Qz  = (float*)(ws + WS_QZ);
  float* cst = (float*)(ws + WS_CONST);

  if (tid < STEPS) {
    const float xv = powf(1.0f - DTF, (float)(tid + 1));
    float s = 0.0f;
    #pragma unroll
    for (int n = 0; n < NB; n++) {
      const float d = xv - cbuf[n];
      s += expf(-hbuf[n] * d * d);
    }
    xs[tid] = xv;
    inv[tid] = xv / s;
  }
  __syncthreads();

  // per-substep affine map: s' = M s + e2*dt*(C1*goal + fx),
  // M = [[1, dt], [-C1*dt, 1-AZ*dt]]
  const double m00 = 1.0, m01 = DTD, m10 = -C1D * DTD, m11 = 1.0 - AZD * DTD;
  double vy[10], vz[10];
  {
    double uy = 0.0, uz = DTD;            // u_j = M^j e2 dt
    #pragma unroll
    for (int j = 0; j < 10; j++) {
      vy[9 - j] = uy; vz[9 - j] = uz;     // v_i = M^{9-i} e2 dt
      const double ty = m00 * uy + m01 * uz;
      const double tz = m10 * uy + m11 * uz;
      uy = ty; uz = tz;
    }
  }
  for (int cell = tid; cell < TPTS * 32; cell += 512) {
    const int k = cell >> 5, n = cell & 31;
    float qyf = 0.0f, qzf = 0.0f;
    if (n < NB) {
      const float cn = cbuf[n], hn = hbuf[n];
      double qy = 0.0, qz = 0.0;
      #pragma unroll
      for (int i = 0; i < 10; i++) {
        const int t = 10 * k + i;
        const float xv = xs[t];
        const float d = xv - cn;
        const float p = expf(-hn * d * d) * inv[t];
        qy += (double)p * vy[i];
        qz += (double)p * vz[i];
      }
      qyf = (float)qy; qzf = (float)qz;
    }
    Qy[cell] = qyf;
    Qz[cell] = qzf;
  }
  if (tid == 0) {
    double ay = 0.0, az = 0.0;
    double uy = 0.0, uz = DTD;
    double p00 = 1, p01 = 0, p10 = 0, p11 = 1;
    for (int j = 0; j < 10; j++) {
      ay += uy; az += uz;
      const double ty = m00 * uy + m01 * uz;
      const double tz = m10 * uy + m11 * uz;
      uy = ty; uz = tz;
      const double a2 = m00 * p00 + m01 * p10;
      const double b2 = m00 * p01 + m01 * p11;
      const double c2 = m10 * p00 + m11 * p10;
      const double d2 = m10 * p01 + m11 * p11;
      p00 = a2; p01 = b2; p10 = c2; p11 = d2;
    }
    cst[0] = (float)p00; cst[1] = (float)p01;
    cst[2] = (float)p10; cst[3] = (float)p11;
    cst[4] = (float)(ay * C1D);
    cst[5] = (float)(az * C1D);
    cst[6] = 0.0f; cst[7] = 0.0f;
  }
}

// ---------------------------------------------------------------------------
// Kernel 2: fused MFMA-MLP + rollout. Block = 16 batch rows, 512 threads.
//   top    : issue x-fragment loads + Q/cst LDS staging (latency hidden by A)
//   stage A: feat = tanh(x@W_pt+b_pt)   (8 waves x 2 ct-tiles) -> LDS bf16
//   stage B: orow = feat@W_last+b_last  (7 waves x 2 ct-tiles) -> LDS f32
//   stage C: rollout, 4 lanes/element (8-wide slices, shfl_xor 1,2)
// ---------------------------------------------------------------------------
__global__ __launch_bounds__(512) void fused_kernel(
    const float* __restrict__ x,
    const float* __restrict__ state,
    const float* __restrict__ b_pt, const float* __restrict__ b_last,
    const char* __restrict__ ws,
    float* __restrict__ out) {
  const short* Wt_pt   = (const short*)(ws + WS_WTPT);
  const short* Wt_last = (const short*)(ws + WS_WTLAST);
  const float* Qyg     = (const float*)(ws + WS_QY);
  const float* Qzg     = (const float*)(ws + WS_QZ);
  const float* cstg    = (const float*)(ws + WS_CONST);

  __shared__ __align__(16) short feat[16 * 264];   // 8448 B
  __shared__ __align__(16) float orow[16][224];    // 14336 B
  __shared__ __align__(16) float sQy[TPTS * 32];   // 6400 B
  __shared__ __align__(16) float sQz[TPTS * 32];   // 6400 B
  __shared__ float sc[8];

  const int tid = threadIdx.x;
  const int w   = tid >> 6;             // wave 0..7
  const int l   = tid & 63;
  const int lr  = l & 15;               // fragment row (A) / col (B,D)
  const int lg  = l >> 4;               // k-group (8 elems each)
  const int row_blk = blockIdx.x * 16;

  // ---- top: independent global traffic, issued before any compute ----
  const float* xr = x + (size_t)(row_blk + lr) * DIN + lg * 8;
  const float4 f0 = ((const float4*)xr)[0];
  const float4 f1 = ((const float4*)xr)[1];
  const float4 g0 = ((const float4*)(xr + 32))[0];
  const float4 g1 = ((const float4*)(xr + 32))[1];
  {
    const float4* gy = (const float4*)Qyg;
    const float4* gz = (const float4*)Qzg;
    float4* dy = (float4*)sQy;
    float4* dz = (float4*)sQz;
    for (int i = tid; i < 400; i += 512) { dy[i] = gy[i]; dz[i] = gz[i]; }
    if (tid < 8) sc[tid] = cstg[tid];
  }

  // ---- stage A: feat = tanh(x @ W_pt + b_pt); wave w owns ct = 2w, 2w+1 ----
  short8 a0, a1;
  a0[0]=f2bf(f0.x); a0[1]=f2bf(f0.y); a0[2]=f2bf(f0.z); a0[3]=f2bf(f0.w);
  a0[4]=f2bf(f1.x); a0[5]=f2bf(f1.y); a0[6]=f2bf(f1.z); a0[7]=f2bf(f1.w);
  a1[0]=f2bf(g0.x); a1[1]=f2bf(g0.y); a1[2]=f2bf(g0.z); a1[3]=f2bf(g0.w);
  a1[4]=f2bf(g1.x); a1[5]=f2bf(g1.y); a1[6]=f2bf(g1.z); a1[7]=f2bf(g1.w);
  {
    f32x4 accA[2];
    #pragma unroll
    for (int t = 0; t < 2; t++) accA[t] = (f32x4){0.f, 0.f, 0.f, 0.f};
    #pragma unroll
    for (int t = 0; t < 2; t++) {
      const int ct = 2 * w + t;
      short8 b0 = *(const short8*)(Wt_pt + (16 * ct + lr) * 64 + 0  + lg * 8);
      short8 b1 = *(const short8*)(Wt_pt + (16 * ct + lr) * 64 + 32 + lg * 8);
      accA[t] = __builtin_amdgcn_mfma_f32_16x16x32_bf16(a0, b0, accA[t], 0, 0, 0);
      accA[t] = __builtin_amdgcn_mfma_f32_16x16x32_bf16(a1, b1, accA[t], 0, 0, 0);
    }
    #pragma unroll
    for (int t = 0; t < 2; t++) {
      const int col = 16 * (2 * w + t) + lr;
      const float bias = b_pt[col];
      #pragma unroll
      for (int i = 0; i < 4; i++) {
        feat[(lg * 4 + i) * 264 + col] = f2bf(tanh_fast(accA[t][i] + bias));
      }
    }
  }
  __syncthreads();   // feat + Q tables ready

  // ---- stage B: orow = feat @ W_last + b_last; waves 0..6, 2 tiles each ----
  if (w < 7) {
    f32x4 accB[2];
    #pragma unroll
    for (int t = 0; t < 2; t++) accB[t] = (f32x4){0.f, 0.f, 0.f, 0.f};
    #pragma unroll
    for (int k0 = 0; k0 < 256; k0 += 32) {
      short8 af = *(const short8*)(feat + lr * 264 + k0 + lg * 8);
      #pragma unroll
      for (int t = 0; t < 2; t++) {
        const int ct = 2 * w + t;
        short8 bf = *(const short8*)(Wt_last + (16 * ct + lr) * 256 + k0 + lg * 8);
        accB[t] = __builtin_amdgcn_mfma_f32_16x16x32_bf16(af, bf, accB[t], 0, 0, 0);
      }
    }
    #pragma unroll
    for (int t = 0; t < 2; t++) {
      const int col = 16 * (2 * w + t) + lr;
      const float bias = (col < OUTC) ? b_last[col] : 0.0f;
      #pragma unroll
      for (int i = 0; i < 4; i++) {
        orow[lg * 4 + i][col] = accB[t][i] + bias;
      }
    }
  }
  __syncthreads();   // orow ready

  // ---- stage C: rollout; 4 lanes per element, 112 elements ----
  const int q  = tid & 3;          // 8-wide quarter of the 32-dot
  const int el = tid >> 2;         // 0..127; active < 112
  if (el < 112) {
    const int bl = el / DOF;       // batch row within block (0..15)
    const int d  = el - bl * DOF;  // dof

    float wq[8];
    #pragma unroll
    for (int j = 0; j < 8; j++) {
      const int n = 8 * q + j;
      wq[j] = (n < NB) ? orow[bl][DOF + d * NB + n] : 0.0f;
    }
    const float goal = orow[bl][d];
    const int eg = (row_blk + bl) * DOF + d;
    float y = state[eg];
    float z = 0.05f;               // dy0 * TAU
    const float gy0 = goal - y;

    const float m00 = sc[0], m01 = sc[1], m10 = sc[2], m11 = sc[3];
    const float uy = sc[4] * goal;
    const float uz = sc[5] * goal;

    const int outbase = (row_blk + bl) * ((TPTS + 1) * DOF) + d;
    if (q == 0) out[outbase] = y;  // t = 0 sample

    for (int k = 0; k < TPTS; k++) {
      const float4* qy4 = (const float4*)(sQy + k * 32 + 8 * q);
      const float4* qz4 = (const float4*)(sQz + k * 32 + 8 * q);
      const float4 ya = qy4[0], yb = qy4[1];
      const float4 za = qz4[0], zb = qz4[1];
      float fy = 0.0f, fz = 0.0f;
      fy = fmaf(wq[0], ya.x, fy); fy = fmaf(wq[1], ya.y, fy);
      fy = fmaf(wq[2], ya.z, fy); fy = fmaf(wq[3], ya.w, fy);
      fy = fmaf(wq[4], yb.x, fy); fy = fmaf(wq[5], yb.y, fy);
      fy = fmaf(wq[6], yb.z, fy); fy = fmaf(wq[7], yb.w, fy);
      fz = fmaf(wq[0], za.x, fz); fz = fmaf(wq[1], za.y, fz);
      fz = fmaf(wq[2], za.z, fz); fz = fmaf(wq[3], za.w, fz);
      fz = fmaf(wq[4], zb.x, fz); fz = fmaf(wq[5], zb.y, fz);
      fz = fmaf(wq[6], zb.z, fz); fz = fmaf(wq[7], zb.w, fz);
      // butterfly reduce across the 4-lane group
      fy += __shfl_xor(fy, 1); fy += __shfl_xor(fy, 2);
      fz += __shfl_xor(fz, 1); fz += __shfl_xor(fz, 2);
      const float ny = fmaf(m00, y, fmaf(m01, z, fmaf(gy0, fy, uy)));
      const float nz = fmaf(m10, y, fmaf(m11, z, fmaf(gy0, fz, uz)));
      y = ny; z = nz;
      if (q == 0) out[outbase + (k + 1) * DOF] = y;
    }
  }
}

// ---------------------------------------------------------------------------
extern "C" void kernel_launch(void* const* d_in, const int* in_sizes, int n_in,
                              void* d_out, int out_size, void* d_ws, size_t ws_size,
                              hipStream_t stream) {
  const float* x      = (const float*)d_in[0];
  const float* state  = (const float*)d_in[1];
  const float* W_pt   = (const float*)d_in[2];
  const float* b_pt   = (const float*)d_in[3];
  const float* W_last = (const float*)d_in[4];
  const float* b_last = (const float*)d_in[5];
  const float* c      = (const float*)d_in[6];
  const float* h      = (const float*)d_in[7];
  float* out = (float*)d_out;

  char* ws = (char*)d_ws;

  // 144 transpose blocks + 1 Q block
  prep_kernel<<<145, 512, 0, stream>>>(c, h, W_pt, W_last, ws);
  fused_kernel<<<BATCH / 16, 512, 0, stream>>>(x, state, b_pt, b_last, ws, out);
}